// Round 1
// baseline (862.809 us; speedup 1.0000x reference)
//
#include <hip/hip_runtime.h>

#define NUM_TEAMS 100000
#define EMBED     32
#define N_EDGES   2000000
#define BQ        524288
#define TARGET_DIM 3

// ---------------- CSR build ----------------

__global__ void hist_kernel(const int* __restrict__ dst, int* __restrict__ deg, int n) {
    int i = blockIdx.x * blockDim.x + threadIdx.x;
    if (i < n) atomicAdd(&deg[dst[i]], 1);
}

// Single-block scan: reads deg (in `degcur`), writes exclusive prefix into
// row_ptr[i] and also into degcur[i] (cursor start positions for fill).
__global__ void scan_kernel(int* __restrict__ degcur, int* __restrict__ row_ptr, int n) {
    __shared__ int buf[1024];
    __shared__ int carry;
    int t = threadIdx.x;
    if (t == 0) carry = 0;
    __syncthreads();
    for (int base = 0; base < n; base += 1024) {
        int i = base + t;
        int v = (i < n) ? degcur[i] : 0;
        buf[t] = v;
        __syncthreads();
        for (int off = 1; off < 1024; off <<= 1) {
            int tmp = (t >= off) ? buf[t - off] : 0;
            __syncthreads();
            buf[t] += tmp;
            __syncthreads();
        }
        int cbase = carry;
        int excl  = buf[t] - v;          // exclusive within chunk
        if (i < n) { row_ptr[i] = cbase + excl; degcur[i] = cbase + excl; }
        int total = buf[1023];
        __syncthreads();                 // all reads of carry/buf done
        if (t == 0) carry = cbase + total;
        __syncthreads();
    }
    if (t == 0) row_ptr[n] = carry;
}

__global__ void fill_kernel(const int* __restrict__ src, const int* __restrict__ dst,
                            const float* __restrict__ ew, int* __restrict__ cursor,
                            int* __restrict__ es, float* __restrict__ ewl, int n) {
    int i = blockIdx.x * blockDim.x + threadIdx.x;
    if (i < n) {
        int d = dst[i];
        int p = atomicAdd(&cursor[d], 1);
        es[p]  = src[i];
        ewl[p] = ew[i];
    }
}

// ---------------- fused GraphConv layer ----------------
// block = 256 threads = 8 nodes x 32 lanes. lane = embedding dim.
// Phase 1: gather-aggregate agg[d] = sum_e w_e * x[src_e][d]  (coalesced 128B rows)
// Phase 2: out[j] = b[j] + sum_d Wrel[j][d]*agg[d] + Wroot[j][d]*x[d], leaky-relu.
#define NODES_PER_BLOCK 8
__global__ void __launch_bounds__(256) conv_kernel(
        const float* __restrict__ x,
        const int* __restrict__ row_ptr,
        const int* __restrict__ es, const float* __restrict__ ewl,
        const float* __restrict__ w_rel,   // [32][32] row-major
        const float* __restrict__ b_rel,   // [32]
        const float* __restrict__ w_root,  // [32][32]
        float* __restrict__ x_out, int num_nodes) {
    __shared__ float s_wrelT[32 * 32];   // transposed: [d][j]
    __shared__ float s_wrootT[32 * 32];
    __shared__ float s_b[32];
    __shared__ float s_agg[NODES_PER_BLOCK][32];
    __shared__ float s_x[NODES_PER_BLOCK][32];

    int t = threadIdx.x;
    for (int i = t; i < 1024; i += 256) {
        int j = i >> 5, d = i & 31;
        s_wrelT[d * 32 + j]  = w_rel[i];
        s_wrootT[d * 32 + j] = w_root[i];
    }
    if (t < 32) s_b[t] = b_rel[t];

    int local = t >> 5;        // node within block
    int lane  = t & 31;        // embedding dim
    int node  = blockIdx.x * NODES_PER_BLOCK + local;

    float acc = 0.f, xv = 0.f;
    if (node < num_nodes) {
        xv = x[node * EMBED + lane];
        int r0 = row_ptr[node], r1 = row_ptr[node + 1];
        for (int k = r0; k < r1; ++k) {
            int   s = es[k];      // broadcast within 32-lane group
            float w = ewl[k];
            acc += w * x[s * EMBED + lane];
        }
    }
    s_agg[local][lane] = acc;
    s_x[local][lane]   = xv;
    __syncthreads();

    if (node < num_nodes) {
        float o = s_b[lane];
        #pragma unroll
        for (int d = 0; d < 32; ++d) {
            o += s_wrelT[d * 32 + lane] * s_agg[local][d]
               + s_wrootT[d * 32 + lane] * s_x[local][d];
        }
        o = (o >= 0.f) ? o : 0.01f * o;
        x_out[node * EMBED + lane] = o;
    }
}

// ---------------- final pair MLP + log_softmax ----------------
__global__ void __launch_bounds__(256) mlp_kernel(
        const float* __restrict__ x,
        const int* __restrict__ home, const int* __restrict__ away,
        const float* __restrict__ w0, const float* __restrict__ b0,
        const float* __restrict__ w1, const float* __restrict__ b1,
        const float* __restrict__ w2, const float* __restrict__ b2,
        const float* __restrict__ w3, const float* __restrict__ b3,
        const float* __restrict__ w4, const float* __restrict__ b4,
        float* __restrict__ out, int n) {
    __shared__ float s_w0[512], s_w1[64], s_w2[64], s_w3[64], s_w4[24];
    __shared__ float s_b0[8], s_b1[8], s_b2[8], s_b3[8], s_b4[3];
    int t = threadIdx.x;
    for (int i = t; i < 512; i += 256) s_w0[i] = w0[i];
    if (t < 64) { s_w1[t] = w1[t]; s_w2[t] = w2[t]; s_w3[t] = w3[t]; }
    if (t < 24) s_w4[t] = w4[t];
    if (t < 8)  { s_b0[t] = b0[t]; s_b1[t] = b1[t]; s_b2[t] = b2[t]; s_b3[t] = b3[t]; }
    if (t < 3)  s_b4[t] = b4[t];
    __syncthreads();

    int i = blockIdx.x * 256 + t;
    if (i >= n) return;

    float hv[64];
    {
        const float4* ph = (const float4*)(x + (size_t)home[i] * EMBED);
        const float4* pa = (const float4*)(x + (size_t)away[i] * EMBED);
        #pragma unroll
        for (int q = 0; q < 8; ++q) {
            float4 v = ph[q];
            hv[4*q+0] = v.x; hv[4*q+1] = v.y; hv[4*q+2] = v.z; hv[4*q+3] = v.w;
        }
        #pragma unroll
        for (int q = 0; q < 8; ++q) {
            float4 v = pa[q];
            hv[32+4*q+0] = v.x; hv[32+4*q+1] = v.y; hv[32+4*q+2] = v.z; hv[32+4*q+3] = v.w;
        }
    }

    float h1[8];
    #pragma unroll
    for (int j = 0; j < 8; ++j) {
        float o = s_b0[j];
        #pragma unroll
        for (int d = 0; d < 64; ++d) o += s_w0[j * 64 + d] * hv[d];
        h1[j] = (o >= 0.f) ? o : 0.01f * o;
    }
    float h2[8];
    #pragma unroll
    for (int j = 0; j < 8; ++j) {
        float o = s_b1[j];
        #pragma unroll
        for (int d = 0; d < 8; ++d) o += s_w1[j * 8 + d] * h1[d];
        h2[j] = (o >= 0.f) ? o : 0.01f * o;
    }
    float h3[8];
    #pragma unroll
    for (int j = 0; j < 8; ++j) {
        float o = s_b2[j];
        #pragma unroll
        for (int d = 0; d < 8; ++d) o += s_w2[j * 8 + d] * h2[d];
        h3[j] = (o >= 0.f) ? o : 0.01f * o;
    }
    float h4[8];
    #pragma unroll
    for (int j = 0; j < 8; ++j) {
        float o = s_b3[j];
        #pragma unroll
        for (int d = 0; d < 8; ++d) o += s_w3[j * 8 + d] * h3[d];
        h4[j] = (o >= 0.f) ? o : 0.01f * o;
    }
    float f[3];
    #pragma unroll
    for (int j = 0; j < 3; ++j) {
        float o = s_b4[j];
        #pragma unroll
        for (int d = 0; d < 8; ++d) o += s_w4[j * 8 + d] * h4[d];
        f[j] = (o >= 0.f) ? o : 0.01f * o;
    }
    float m  = fmaxf(f[0], fmaxf(f[1], f[2]));
    float s  = expf(f[0] - m) + expf(f[1] - m) + expf(f[2] - m);
    float ls = logf(s);
    out[3 * i + 0] = f[0] - m - ls;
    out[3 * i + 1] = f[1] - m - ls;
    out[3 * i + 2] = f[2] - m - ls;
}

// ---------------- launch ----------------

extern "C" void kernel_launch(void* const* d_in, const int* in_sizes, int n_in,
                              void* d_out, int out_size, void* d_ws, size_t ws_size,
                              hipStream_t stream) {
    const int*   edge_index = (const int*)d_in[0];
    const int*   src   = edge_index;
    const int*   dst   = edge_index + N_EDGES;
    const float* ew    = (const float*)d_in[1];
    const int*   home  = (const int*)d_in[2];
    const int*   away  = (const int*)d_in[3];
    const float* embed = (const float*)d_in[4];
    const float* w_rel  = (const float*)d_in[5];
    const float* b_rel  = (const float*)d_in[6];
    const float* w_root = (const float*)d_in[7];
    const float* w0 = (const float*)d_in[8];  const float* b0 = (const float*)d_in[9];
    const float* w1 = (const float*)d_in[10]; const float* b1 = (const float*)d_in[11];
    const float* w2 = (const float*)d_in[12]; const float* b2 = (const float*)d_in[13];
    const float* w3 = (const float*)d_in[14]; const float* b3 = (const float*)d_in[15];
    const float* w4 = (const float*)d_in[16]; const float* b4 = (const float*)d_in[17];
    float* out = (float*)d_out;

    char* ws = (char*)d_ws;
    size_t off = 0;
    auto carve = [&](size_t bytes) -> void* {
        void* p = ws + off;
        off += (bytes + 15) & ~(size_t)15;
        return p;
    };
    int*   row_ptr = (int*)  carve((NUM_TEAMS + 1) * sizeof(int));
    int*   cursor  = (int*)  carve(NUM_TEAMS * sizeof(int));
    int*   es      = (int*)  carve(N_EDGES * sizeof(int));
    float* ewl     = (float*)carve(N_EDGES * sizeof(float));
    float* x1      = (float*)carve((size_t)NUM_TEAMS * EMBED * sizeof(float));
    float* x2      = (float*)carve((size_t)NUM_TEAMS * EMBED * sizeof(float));
    (void)ws_size; (void)in_sizes; (void)n_in; (void)out_size;

    const int edge_blocks = (N_EDGES + 255) / 256;
    const int conv_blocks = (NUM_TEAMS + NODES_PER_BLOCK - 1) / NODES_PER_BLOCK;
    const int mlp_blocks  = (BQ + 255) / 256;

    hipMemsetAsync(cursor, 0, NUM_TEAMS * sizeof(int), stream);
    hist_kernel<<<edge_blocks, 256, 0, stream>>>(dst, cursor, N_EDGES);
    scan_kernel<<<1, 1024, 0, stream>>>(cursor, row_ptr, NUM_TEAMS);
    fill_kernel<<<edge_blocks, 256, 0, stream>>>(src, dst, ew, cursor, es, ewl, N_EDGES);

    conv_kernel<<<conv_blocks, 256, 0, stream>>>(embed, row_ptr, es, ewl,
        w_rel + 0 * 1024, b_rel + 0 * 32, w_root + 0 * 1024, x1, NUM_TEAMS);
    conv_kernel<<<conv_blocks, 256, 0, stream>>>(x1, row_ptr, es, ewl,
        w_rel + 1 * 1024, b_rel + 1 * 32, w_root + 1 * 1024, x2, NUM_TEAMS);
    conv_kernel<<<conv_blocks, 256, 0, stream>>>(x2, row_ptr, es, ewl,
        w_rel + 2 * 1024, b_rel + 2 * 32, w_root + 2 * 1024, x1, NUM_TEAMS);

    mlp_kernel<<<mlp_blocks, 256, 0, stream>>>(x1, home, away,
        w0, b0, w1, b1, w2, b2, w3, b3, w4, b4, out, BQ);
}

// Round 2
// 682.854 us; speedup vs baseline: 1.2635x; 1.2635x over previous
//
#include <hip/hip_runtime.h>

#define NUM_TEAMS 100000
#define EMBED     32
#define N_EDGES   2000000
#define BQ        524288
#define TARGET_DIM 3

// ---------------- CSR build ----------------

__global__ void hist_kernel(const int* __restrict__ dst, int* __restrict__ deg, int n) {
    int i = blockIdx.x * blockDim.x + threadIdx.x;
    if (i < n) atomicAdd(&deg[dst[i]], 1);
}

// ---- hierarchical exclusive scan over deg[n] ----
// chunk = 2048 elements per block (256 threads x 8).
#define SCAN_CHUNK 2048

// Kernel A: per-chunk totals.
__global__ void __launch_bounds__(256) scan_partial(const int* __restrict__ deg,
                                                    int* __restrict__ bsum, int n) {
    __shared__ int wsum[4];
    int t = threadIdx.x;
    int base = blockIdx.x * SCAN_CHUNK + t * 8;
    int s = 0;
    #pragma unroll
    for (int k = 0; k < 8; ++k) { int idx = base + k; if (idx < n) s += deg[idx]; }
    #pragma unroll
    for (int off = 32; off > 0; off >>= 1) s += __shfl_down(s, off, 64);
    int lane = t & 63, wid = t >> 6;
    if (lane == 0) wsum[wid] = s;
    __syncthreads();
    if (t == 0) bsum[blockIdx.x] = wsum[0] + wsum[1] + wsum[2] + wsum[3];
}

// Kernel B: exclusive scan of block sums (nb <= 64, one wave).
__global__ void scan_bsums(int* __restrict__ bsum, int nb) {
    int t = threadIdx.x;
    int v = (t < nb) ? bsum[t] : 0;
    int incl = v;
    #pragma unroll
    for (int off = 1; off < 64; off <<= 1) {
        int u = __shfl_up(incl, off, 64);
        if (t >= off) incl += u;
    }
    if (t < nb) bsum[t] = incl - v;   // exclusive
}

// Kernel C: per-chunk exclusive scan + block offset -> row_ptr and cursor.
__global__ void __launch_bounds__(256) scan_apply(const int* __restrict__ deg,
                                                  const int* __restrict__ bofs,
                                                  int* __restrict__ row_ptr,
                                                  int* __restrict__ cursor, int n) {
    __shared__ int wsum[4];
    int t = threadIdx.x;
    int base = blockIdx.x * SCAN_CHUNK + t * 8;
    int v[8];
    int s = 0;
    #pragma unroll
    for (int k = 0; k < 8; ++k) { int idx = base + k; v[k] = (idx < n) ? deg[idx] : 0; s += v[k]; }
    int lane = t & 63, wid = t >> 6;
    int incl = s;
    #pragma unroll
    for (int off = 1; off < 64; off <<= 1) {
        int u = __shfl_up(incl, off, 64);
        if (lane >= off) incl += u;
    }
    if (lane == 63) wsum[wid] = incl;
    __syncthreads();
    int wofs = 0;
    for (int w = 0; w < wid; ++w) wofs += wsum[w];
    int excl = incl - s + wofs + bofs[blockIdx.x];
    #pragma unroll
    for (int k = 0; k < 8; ++k) {
        int idx = base + k;
        if (idx < n) { row_ptr[idx] = excl; cursor[idx] = excl; }
        excl += v[k];
    }
    if (blockIdx.x == gridDim.x - 1 && t == 255) row_ptr[n] = excl;  // == N_EDGES
}

__global__ void fill_kernel(const int* __restrict__ src, const int* __restrict__ dst,
                            const float* __restrict__ ew, int* __restrict__ cursor,
                            int* __restrict__ es, float* __restrict__ ewl, int n) {
    int i = blockIdx.x * blockDim.x + threadIdx.x;
    if (i < n) {
        int d = dst[i];
        int p = atomicAdd(&cursor[d], 1);
        es[p]  = src[i];
        ewl[p] = ew[i];
    }
}

// ---------------- fused GraphConv layer ----------------
// block = 256 threads = 8 nodes x 32 lanes. lane = embedding dim.
#define NODES_PER_BLOCK 8
__global__ void __launch_bounds__(256) conv_kernel(
        const float* __restrict__ x,
        const int* __restrict__ row_ptr,
        const int* __restrict__ es, const float* __restrict__ ewl,
        const float* __restrict__ w_rel,   // [32][32] row-major
        const float* __restrict__ b_rel,   // [32]
        const float* __restrict__ w_root,  // [32][32]
        float* __restrict__ x_out, int num_nodes) {
    __shared__ float s_wrelT[32 * 32];   // transposed: [d][j]
    __shared__ float s_wrootT[32 * 32];
    __shared__ float s_b[32];
    __shared__ float s_agg[NODES_PER_BLOCK][32];
    __shared__ float s_x[NODES_PER_BLOCK][32];

    int t = threadIdx.x;
    for (int i = t; i < 1024; i += 256) {
        int j = i >> 5, d = i & 31;
        s_wrelT[d * 32 + j]  = w_rel[i];
        s_wrootT[d * 32 + j] = w_root[i];
    }
    if (t < 32) s_b[t] = b_rel[t];

    int local = t >> 5;        // node within block
    int lane  = t & 31;        // embedding dim
    int node  = blockIdx.x * NODES_PER_BLOCK + local;

    float acc = 0.f, xv = 0.f;
    if (node < num_nodes) {
        xv = x[node * EMBED + lane];
        int r0 = row_ptr[node], r1 = row_ptr[node + 1];
        for (int k = r0; k < r1; ++k) {
            int   s = es[k];      // broadcast within 32-lane group
            float w = ewl[k];
            acc += w * x[s * EMBED + lane];
        }
    }
    s_agg[local][lane] = acc;
    s_x[local][lane]   = xv;
    __syncthreads();

    if (node < num_nodes) {
        float o = s_b[lane];
        #pragma unroll
        for (int d = 0; d < 32; ++d) {
            o += s_wrelT[d * 32 + lane] * s_agg[local][d]
               + s_wrootT[d * 32 + lane] * s_x[local][d];
        }
        o = (o >= 0.f) ? o : 0.01f * o;
        x_out[node * EMBED + lane] = o;
    }
}

// ---------------- final pair MLP + log_softmax ----------------
__global__ void __launch_bounds__(256) mlp_kernel(
        const float* __restrict__ x,
        const int* __restrict__ home, const int* __restrict__ away,
        const float* __restrict__ w0, const float* __restrict__ b0,
        const float* __restrict__ w1, const float* __restrict__ b1,
        const float* __restrict__ w2, const float* __restrict__ b2,
        const float* __restrict__ w3, const float* __restrict__ b3,
        const float* __restrict__ w4, const float* __restrict__ b4,
        float* __restrict__ out, int n) {
    __shared__ float s_w0[512], s_w1[64], s_w2[64], s_w3[64], s_w4[24];
    __shared__ float s_b0[8], s_b1[8], s_b2[8], s_b3[8], s_b4[3];
    int t = threadIdx.x;
    for (int i = t; i < 512; i += 256) s_w0[i] = w0[i];
    if (t < 64) { s_w1[t] = w1[t]; s_w2[t] = w2[t]; s_w3[t] = w3[t]; }
    if (t < 24) s_w4[t] = w4[t];
    if (t < 8)  { s_b0[t] = b0[t]; s_b1[t] = b1[t]; s_b2[t] = b2[t]; s_b3[t] = b3[t]; }
    if (t < 3)  s_b4[t] = b4[t];
    __syncthreads();

    int i = blockIdx.x * 256 + t;
    if (i >= n) return;

    float hv[64];
    {
        const float4* ph = (const float4*)(x + (size_t)home[i] * EMBED);
        const float4* pa = (const float4*)(x + (size_t)away[i] * EMBED);
        #pragma unroll
        for (int q = 0; q < 8; ++q) {
            float4 v = ph[q];
            hv[4*q+0] = v.x; hv[4*q+1] = v.y; hv[4*q+2] = v.z; hv[4*q+3] = v.w;
        }
        #pragma unroll
        for (int q = 0; q < 8; ++q) {
            float4 v = pa[q];
            hv[32+4*q+0] = v.x; hv[32+4*q+1] = v.y; hv[32+4*q+2] = v.z; hv[32+4*q+3] = v.w;
        }
    }

    float h1[8];
    #pragma unroll
    for (int j = 0; j < 8; ++j) {
        float o = s_b0[j];
        #pragma unroll
        for (int d = 0; d < 64; ++d) o += s_w0[j * 64 + d] * hv[d];
        h1[j] = (o >= 0.f) ? o : 0.01f * o;
    }
    float h2[8];
    #pragma unroll
    for (int j = 0; j < 8; ++j) {
        float o = s_b1[j];
        #pragma unroll
        for (int d = 0; d < 8; ++d) o += s_w1[j * 8 + d] * h1[d];
        h2[j] = (o >= 0.f) ? o : 0.01f * o;
    }
    float h3[8];
    #pragma unroll
    for (int j = 0; j < 8; ++j) {
        float o = s_b2[j];
        #pragma unroll
        for (int d = 0; d < 8; ++d) o += s_w2[j * 8 + d] * h2[d];
        h3[j] = (o >= 0.f) ? o : 0.01f * o;
    }
    float h4[8];
    #pragma unroll
    for (int j = 0; j < 8; ++j) {
        float o = s_b3[j];
        #pragma unroll
        for (int d = 0; d < 8; ++d) o += s_w3[j * 8 + d] * h3[d];
        h4[j] = (o >= 0.f) ? o : 0.01f * o;
    }
    float f[3];
    #pragma unroll
    for (int j = 0; j < 3; ++j) {
        float o = s_b4[j];
        #pragma unroll
        for (int d = 0; d < 8; ++d) o += s_w4[j * 8 + d] * h4[d];
        f[j] = (o >= 0.f) ? o : 0.01f * o;
    }
    float m  = fmaxf(f[0], fmaxf(f[1], f[2]));
    float s  = expf(f[0] - m) + expf(f[1] - m) + expf(f[2] - m);
    float ls = logf(s);
    out[3 * i + 0] = f[0] - m - ls;
    out[3 * i + 1] = f[1] - m - ls;
    out[3 * i + 2] = f[2] - m - ls;
}

// ---------------- launch ----------------

extern "C" void kernel_launch(void* const* d_in, const int* in_sizes, int n_in,
                              void* d_out, int out_size, void* d_ws, size_t ws_size,
                              hipStream_t stream) {
    const int*   edge_index = (const int*)d_in[0];
    const int*   src   = edge_index;
    const int*   dst   = edge_index + N_EDGES;
    const float* ew    = (const float*)d_in[1];
    const int*   home  = (const int*)d_in[2];
    const int*   away  = (const int*)d_in[3];
    const float* embed = (const float*)d_in[4];
    const float* w_rel  = (const float*)d_in[5];
    const float* b_rel  = (const float*)d_in[6];
    const float* w_root = (const float*)d_in[7];
    const float* w0 = (const float*)d_in[8];  const float* b0 = (const float*)d_in[9];
    const float* w1 = (const float*)d_in[10]; const float* b1 = (const float*)d_in[11];
    const float* w2 = (const float*)d_in[12]; const float* b2 = (const float*)d_in[13];
    const float* w3 = (const float*)d_in[14]; const float* b3 = (const float*)d_in[15];
    const float* w4 = (const float*)d_in[16]; const float* b4 = (const float*)d_in[17];
    float* out = (float*)d_out;

    char* ws = (char*)d_ws;
    size_t off = 0;
    auto carve = [&](size_t bytes) -> void* {
        void* p = ws + off;
        off += (bytes + 15) & ~(size_t)15;
        return p;
    };
    int*   row_ptr = (int*)  carve((NUM_TEAMS + 1) * sizeof(int));
    int*   deg     = (int*)  carve(NUM_TEAMS * sizeof(int));
    int*   cursor  = (int*)  carve(NUM_TEAMS * sizeof(int));
    int*   bsum    = (int*)  carve(64 * sizeof(int));
    int*   es      = (int*)  carve(N_EDGES * sizeof(int));
    float* ewl     = (float*)carve(N_EDGES * sizeof(float));
    float* x1      = (float*)carve((size_t)NUM_TEAMS * EMBED * sizeof(float));
    float* x2      = (float*)carve((size_t)NUM_TEAMS * EMBED * sizeof(float));
    (void)ws_size; (void)in_sizes; (void)n_in; (void)out_size;

    const int edge_blocks = (N_EDGES + 255) / 256;
    const int conv_blocks = (NUM_TEAMS + NODES_PER_BLOCK - 1) / NODES_PER_BLOCK;
    const int mlp_blocks  = (BQ + 255) / 256;
    const int scan_blocks = (NUM_TEAMS + SCAN_CHUNK - 1) / SCAN_CHUNK;  // 49

    hipMemsetAsync(deg, 0, NUM_TEAMS * sizeof(int), stream);
    hist_kernel<<<edge_blocks, 256, 0, stream>>>(dst, deg, N_EDGES);
    scan_partial<<<scan_blocks, 256, 0, stream>>>(deg, bsum, NUM_TEAMS);
    scan_bsums<<<1, 64, 0, stream>>>(bsum, scan_blocks);
    scan_apply<<<scan_blocks, 256, 0, stream>>>(deg, bsum, row_ptr, cursor, NUM_TEAMS);
    fill_kernel<<<edge_blocks, 256, 0, stream>>>(src, dst, ew, cursor, es, ewl, N_EDGES);

    conv_kernel<<<conv_blocks, 256, 0, stream>>>(embed, row_ptr, es, ewl,
        w_rel + 0 * 1024, b_rel + 0 * 32, w_root + 0 * 1024, x1, NUM_TEAMS);
    conv_kernel<<<conv_blocks, 256, 0, stream>>>(x1, row_ptr, es, ewl,
        w_rel + 1 * 1024, b_rel + 1 * 32, w_root + 1 * 1024, x2, NUM_TEAMS);
    conv_kernel<<<conv_blocks, 256, 0, stream>>>(x2, row_ptr, es, ewl,
        w_rel + 2 * 1024, b_rel + 2 * 32, w_root + 2 * 1024, x1, NUM_TEAMS);

    mlp_kernel<<<mlp_blocks, 256, 0, stream>>>(x1, home, away,
        w0, b0, w1, b1, w2, b2, w3, b3, w4, b4, out, BQ);
}